// Round 1
// baseline (644.318 us; speedup 1.0000x reference)
//
#include <hip/hip_runtime.h>
#include <hip/hip_bf16.h>

#define B_ROWS 16384
#define DDIM   512
#define NNODES 1023
#define NLEAF  1024
#define ODIM   256
#define LAMDA  1e-3
#define EPSV   1e-7f

typedef __bf16 bf16x8v __attribute__((ext_vector_type(8)));
typedef float  f32x16v __attribute__((ext_vector_type(16)));

// ---------------------------------------------------------------------------
// GEMM1: P[b,n] = sigmoid(beta[n] * (data[b,:] . W[n,1:] + W[n,0]))
// f32 vector SGEMM, 128x128x16 tiles, 256 threads, 8x8 micro-tile.
// ---------------------------------------------------------------------------
#define G1_BM 128
#define G1_BN 128
#define G1_BK 16

__global__ __launch_bounds__(256, 4)
void gemm1_sigmoid(const float* __restrict__ A,    // data [16384,512]
                   const float* __restrict__ W,    // [1023,513]
                   const float* __restrict__ beta, // [1023]
                   float* __restrict__ P)          // [16384,1023]
{
    __shared__ float As[G1_BK][G1_BM];
    __shared__ float Bs[G1_BK][G1_BN];
    const int tid = threadIdx.x;
    const int m0 = blockIdx.x * G1_BM;
    const int n0 = blockIdx.y * G1_BN;
    const int tx = tid & 15;
    const int ty = tid >> 4;

    float acc[8][8];
#pragma unroll
    for (int i = 0; i < 8; ++i)
#pragma unroll
        for (int j = 0; j < 8; ++j) acc[i][j] = 0.f;

    const int ar0 = tid >> 2;         // 0..63
    const int ac0 = (tid & 3) << 2;   // 0,4,8,12

    for (int k0 = 0; k0 < DDIM; k0 += G1_BK) {
        // A tile: As[c][r] = A[m0+r][k0+c]
#pragma unroll
        for (int h = 0; h < 2; ++h) {
            int r = ar0 + h * 64;
            const float4 v = *reinterpret_cast<const float4*>(
                &A[(size_t)(m0 + r) * DDIM + k0 + ac0]);
            As[ac0 + 0][r] = v.x;
            As[ac0 + 1][r] = v.y;
            As[ac0 + 2][r] = v.z;
            As[ac0 + 3][r] = v.w;
        }
        // B tile: Bs[c][n] = W[n0+n][k0+c+1]  (unaligned row -> scalar loads)
#pragma unroll
        for (int h = 0; h < 2; ++h) {
            int n = ar0 + h * 64;
            int gn = n0 + n;
            if (gn < NNODES) {
                const float* wr = &W[(size_t)gn * 513 + k0 + 1 + ac0];
#pragma unroll
                for (int jj = 0; jj < 4; ++jj) Bs[ac0 + jj][n] = wr[jj];
            } else {
#pragma unroll
                for (int jj = 0; jj < 4; ++jj) Bs[ac0 + jj][n] = 0.f;
            }
        }
        __syncthreads();
#pragma unroll
        for (int kk = 0; kk < G1_BK; ++kk) {
            float a[8], b[8];
            *reinterpret_cast<float4*>(&a[0]) = *reinterpret_cast<const float4*>(&As[kk][ty * 4]);
            *reinterpret_cast<float4*>(&a[4]) = *reinterpret_cast<const float4*>(&As[kk][ty * 4 + 64]);
            *reinterpret_cast<float4*>(&b[0]) = *reinterpret_cast<const float4*>(&Bs[kk][tx * 4]);
            *reinterpret_cast<float4*>(&b[4]) = *reinterpret_cast<const float4*>(&Bs[kk][tx * 4 + 64]);
#pragma unroll
            for (int i = 0; i < 8; ++i)
#pragma unroll
                for (int j = 0; j < 8; ++j)
                    acc[i][j] = fmaf(a[i], b[j], acc[i][j]);
        }
        __syncthreads();
    }
    // epilogue: bias, beta, sigmoid
#pragma unroll
    for (int j = 0; j < 8; ++j) {
        int n = n0 + tx * 4 + (j & 3) + (j >> 2) * 64;
        if (n >= NNODES) continue;
        float w0 = W[(size_t)n * 513];
        float bt = beta[n];
#pragma unroll
        for (int i = 0; i < 8; ++i) {
            int m = m0 + ty * 4 + (i & 3) + (i >> 2) * 64;
            float s = bt * (acc[i][j] + w0);
            float pv = 1.f / (1.f + expf(-s));   // safe in f32: expf->inf => pv=0
            P[(size_t)m * NNODES + n] = pv;
        }
    }
}

// ---------------------------------------------------------------------------
// Tree pass: per row, compute leaf probabilities mu (f32), write bf16 mu,
// per-group partial argmax, and leaf column sums (atomics).
// Grid = 64 row-blocks x 8 subtree-groups. Thread = one row.
// ---------------------------------------------------------------------------
__global__ __launch_bounds__(256, 2)
void tree_pass(const float* __restrict__ P,
               __hip_bfloat16* __restrict__ MU,   // [16384,1024]
               float* __restrict__ leafsum,       // [1024] (pre-zeroed)
               float* __restrict__ pval,          // [8][16384]
               int*   __restrict__ pidx)          // [8][16384]
{
    const int tid = threadIdx.x;
    const int rb = blockIdx.x & 63;
    const int g  = blockIdx.x >> 6;        // subtree group 0..7 (4 subtrees each)
    const int b  = rb * 256 + tid;
    __shared__ float sp[256][33];          // 31 staged nodes per row (+pad)

    // ---- phase A: stage nodes 0..30 (top 5 layers), coalesced ----
    for (int idx = tid; idx < 256 * 32; idx += 256) {
        int r = idx >> 5, c = idx & 31;
        if (c < 31) sp[r][c + 1] = P[(size_t)(rb * 256 + r) * NNODES + c];
    }
    __syncthreads();

    float v[64];
    v[1] = 1.f;
#pragma unroll
    for (int u = 1; u < 32; ++u) {
        float pu = sp[tid][u];
        v[2 * u]     = v[u] * pu;
        v[2 * u + 1] = v[u] * (1.f - pu);
    }
    // v[32+t] = mu after top 5 layers (t = 5-bit path)

    float bestv = -1.f;
    int besti = 0;

    for (int tt = 0; tt < 4; ++tt) {
        const int t = g * 4 + tt;
        __syncthreads();                   // protect sp before overwrite
        // stage subtree t: local heap u=1..31 -> global node
        for (int idx = tid; idx < 256 * 32; idx += 256) {
            int r = idx >> 5, c = idx & 31;
            if (c < 31) {
                int u = c + 1;
                int lvl = 31 - __clz(u);                       // 0..4
                int node = ((32 << lvl) - 1) + t * (1 << lvl) + (u - (1 << lvl));
                sp[r][u] = P[(size_t)(rb * 256 + r) * NNODES + node];
            }
        }
        __syncthreads();

        float w[64];
        w[1] = v[32 + t];
#pragma unroll
        for (int u = 1; u < 32; ++u) {
            float pu = sp[tid][u];
            w[2 * u]     = w[u] * pu;
            w[2 * u + 1] = w[u] * (1.f - pu);
        }
        // leaves: w[32+q], global leaf = t*32+q
        __align__(16) __hip_bfloat16 mb[32];
#pragma unroll
        for (int q = 0; q < 32; ++q) mb[q] = __float2bfloat16(w[32 + q]);
        {
            const ulonglong2* src = reinterpret_cast<const ulonglong2*>(mb);
            ulonglong2* dst = reinterpret_cast<ulonglong2*>(&MU[(size_t)b * NLEAF + t * 32]);
#pragma unroll
            for (int h = 0; h < 4; ++h) dst[h] = src[h];
        }
#pragma unroll
        for (int q = 0; q < 32; ++q) {
            float lv = w[32 + q];
            if (lv > bestv) { bestv = lv; besti = t * 32 + q; }
            float s = lv;
#pragma unroll
            for (int m = 1; m < 64; m <<= 1) s += __shfl_xor(s, m, 64);
            if ((tid & 63) == 0) atomicAdd(&leafsum[t * 32 + q], s);
        }
    }
    pval[(size_t)g * B_ROWS + b] = bestv;
    pidx[(size_t)g * B_ROWS + b] = besti;
}

__global__ void argmax_finalize(const float* __restrict__ pval,
                                const int* __restrict__ pidx,
                                int* __restrict__ ids)
{
    int b = blockIdx.x * 256 + threadIdx.x;
    float bv = -1.f; int bi = 0;
    for (int g = 0; g < 8; ++g) {          // ascending g = ascending leaf index
        float v = pval[(size_t)g * B_ROWS + b];
        if (v > bv) { bv = v; bi = pidx[(size_t)g * B_ROWS + b]; }
    }
    ids[b] = bi;
}

// ---------------------------------------------------------------------------
// softmax over param rows -> logdist (f32, for prediction) + distT (bf16, [O][L])
// ---------------------------------------------------------------------------
__global__ __launch_bounds__(256)
void softmax_param(const float* __restrict__ param,   // [1024,256]
                   float* __restrict__ logdist,       // [1024,256]
                   __hip_bfloat16* __restrict__ distT)// [256,1024]
{
    __shared__ float red[4], red2[4];
    int l = blockIdx.x;
    int o = threadIdx.x;
    float x = param[(size_t)l * ODIM + o];
    float m = x;
#pragma unroll
    for (int s = 1; s < 64; s <<= 1) m = fmaxf(m, __shfl_xor(m, s, 64));
    if ((o & 63) == 0) red[o >> 6] = m;
    __syncthreads();
    m = fmaxf(fmaxf(red[0], red[1]), fmaxf(red[2], red[3]));
    float e = expf(x - m);
    float s = e;
#pragma unroll
    for (int k = 1; k < 64; k <<= 1) s += __shfl_xor(s, k, 64);
    if ((o & 63) == 0) red2[o >> 6] = s;
    __syncthreads();
    s = red2[0] + red2[1] + red2[2] + red2[3];
    float d = e / s;
    logdist[(size_t)l * ODIM + o] = logf(d);
    distT[(size_t)o * NLEAF + l] = __float2bfloat16(d);
}

// ---------------------------------------------------------------------------
// penalty: heap-aggregate leaf colsums, sum log(alpha)+log(1-alpha) terms.
// ---------------------------------------------------------------------------
__global__ __launch_bounds__(256)
void penalty_kernel(const float* __restrict__ leafsum, float* __restrict__ out_pen)
{
    __shared__ float M[2048];
    __shared__ double dred[256];
    int tid = threadIdx.x;
    for (int i = tid; i < 1024; i += 256) M[1024 + i] = leafsum[i];
    __syncthreads();
    for (int n = 512; n >= 1; n >>= 1) {
        for (int u = n + tid; u < 2 * n; u += 256) M[u] = M[2 * u] + M[2 * u + 1];
        __syncthreads();
    }
    double acc = 0.0;
    for (int u = 2 + tid; u < 2048; u += 256) {
        int lvl = 31 - __clz(u);                    // 1..10 == layer+1
        float a = M[u] / (M[u >> 1] + EPSV);
        a = fminf(fmaxf(a, EPSV), 1.f - EPSV);
        float term = logf(a) + logf(1.f - a);
        acc -= ldexp((double)LAMDA * 0.5, 1 - lvl) * (double)term;
    }
    dred[tid] = acc;
    __syncthreads();
    for (int s = 128; s > 0; s >>= 1) {
        if (tid < s) dred[tid] += dred[tid + s];
        __syncthreads();
    }
    if (tid == 0) out_pen[0] = (float)dred[0];
}

// ---------------------------------------------------------------------------
// GEMM2: out1 = log(mu @ dist) via bf16 MFMA 32x32x16.
// Block: 256 thr = 4 waves; tile M=32 (shared), each wave handles 64 cols.
// ---------------------------------------------------------------------------
__global__ __launch_bounds__(256)
void gemm2_log(const __hip_bfloat16* __restrict__ MU,  // [16384,1024]
               const __hip_bfloat16* __restrict__ DT,  // [256,1024]
               float* __restrict__ out1)               // [16384,256]
{
    __shared__ __align__(16) __hip_bfloat16 ldsB[256][40]; // [n][k], +8 pad
    __shared__ __align__(16) __hip_bfloat16 ldsA[32][40];  // [m][k], +8 pad
    const int tid = threadIdx.x;
    const int lane = tid & 63;
    const int wv = tid >> 6;
    const int m0 = blockIdx.x * 32;
    const int n0w = wv * 64;
    const int lr = lane & 31;
    const int lh = lane >> 5;

    f32x16v acc0 = {}; f32x16v acc1 = {};

    for (int k0 = 0; k0 < NLEAF; k0 += 32) {
        __syncthreads();
        {   // stage B slice: DT[n=tid][k0..k0+31]
            const ulonglong2* src = reinterpret_cast<const ulonglong2*>(&DT[(size_t)tid * NLEAF + k0]);
            ulonglong2* dst = reinterpret_cast<ulonglong2*>(&ldsB[tid][0]);
#pragma unroll
            for (int h = 0; h < 4; ++h) dst[h] = src[h];
        }
        if (tid < 128) {  // stage A slice: MU[m0+r][k0..k0+31]
            int r = tid >> 2, cc = (tid & 3) * 8;
            *reinterpret_cast<ulonglong2*>(&ldsA[r][cc]) =
                *reinterpret_cast<const ulonglong2*>(&MU[(size_t)(m0 + r) * NLEAF + k0 + cc]);
        }
        __syncthreads();
        bf16x8v a0 = *reinterpret_cast<const bf16x8v*>(&ldsA[lr][lh * 8]);
        bf16x8v a1 = *reinterpret_cast<const bf16x8v*>(&ldsA[lr][16 + lh * 8]);
        bf16x8v b00 = *reinterpret_cast<const bf16x8v*>(&ldsB[n0w + lr][lh * 8]);
        bf16x8v b01 = *reinterpret_cast<const bf16x8v*>(&ldsB[n0w + lr][16 + lh * 8]);
        bf16x8v b10 = *reinterpret_cast<const bf16x8v*>(&ldsB[n0w + 32 + lr][lh * 8]);
        bf16x8v b11 = *reinterpret_cast<const bf16x8v*>(&ldsB[n0w + 32 + lr][16 + lh * 8]);
        acc0 = __builtin_amdgcn_mfma_f32_32x32x16_bf16(a0, b00, acc0, 0, 0, 0);
        acc0 = __builtin_amdgcn_mfma_f32_32x32x16_bf16(a1, b01, acc0, 0, 0, 0);
        acc1 = __builtin_amdgcn_mfma_f32_32x32x16_bf16(a0, b10, acc1, 0, 0, 0);
        acc1 = __builtin_amdgcn_mfma_f32_32x32x16_bf16(a1, b11, acc1, 0, 0, 0);
    }
    // D layout: col = lane&31, row = (reg&3) + 8*(reg>>2) + 4*(lane>>5)
#pragma unroll
    for (int r = 0; r < 16; ++r) {
        int row = (r & 3) + 8 * (r >> 2) + 4 * lh;
        size_t base = (size_t)(m0 + row) * ODIM + n0w + lr;
        out1[base]      = logf(acc0[r]);
        out1[base + 32] = logf(acc1[r]);
    }
}

__global__ void gather_logpred(const float* __restrict__ logdist,
                               const int* __restrict__ ids,
                               float* __restrict__ out0)
{
    int b = blockIdx.x;
    int o = threadIdx.x;
    int id = ids[b];
    out0[(size_t)b * ODIM + o] = logdist[(size_t)id * ODIM + o];
}

__global__ void copy_w(const float* __restrict__ W, float* __restrict__ outW)
{
    int i = blockIdx.x * 256 + threadIdx.x;
    if (i < NNODES * 513) outW[i] = W[i];
}

// ---------------------------------------------------------------------------
extern "C" void kernel_launch(void* const* d_in, const int* in_sizes, int n_in,
                              void* d_out, int out_size, void* d_ws, size_t ws_size,
                              hipStream_t stream)
{
    (void)in_sizes; (void)n_in; (void)out_size; (void)ws_size;
    const float* data  = (const float*)d_in[0];
    const float* W     = (const float*)d_in[1];
    const float* beta  = (const float*)d_in[2];
    const float* param = (const float*)d_in[3];
    float* out = (float*)d_out;

    char* ws = (char*)d_ws;
    size_t off = 0;
    float* P = (float*)(ws + off);               off += (size_t)B_ROWS * NNODES * 4;
    __hip_bfloat16* MU = (__hip_bfloat16*)(ws + off); off += (size_t)B_ROWS * NLEAF * 2;
    __hip_bfloat16* DT = (__hip_bfloat16*)(ws + off); off += (size_t)ODIM * NLEAF * 2;
    float* logdist = (float*)(ws + off);         off += (size_t)NLEAF * ODIM * 4;
    int*   ids     = (int*)(ws + off);           off += (size_t)B_ROWS * 4;
    float* leafsum = (float*)(ws + off);         off += (size_t)NLEAF * 4;
    float* pval    = (float*)(ws + off);         off += (size_t)8 * B_ROWS * 4;
    int*   pidx    = (int*)(ws + off);           off += (size_t)8 * B_ROWS * 4;
    // total ws use: ~103.3 MB

    float* out_logpred = out;
    float* out_logout  = out + (size_t)B_ROWS * ODIM;
    float* out_pen     = out + 2 * (size_t)B_ROWS * ODIM;
    float* out_W       = out_pen + 1;

    hipMemsetAsync(leafsum, 0, NLEAF * 4, stream);

    softmax_param<<<NLEAF, 256, 0, stream>>>(param, logdist, DT);

    dim3 g1grid(B_ROWS / G1_BM, (NNODES + G1_BN - 1) / G1_BN);
    gemm1_sigmoid<<<g1grid, 256, 0, stream>>>(data, W, beta, P);

    tree_pass<<<512, 256, 0, stream>>>(P, MU, leafsum, pval, pidx);
    argmax_finalize<<<B_ROWS / 256, 256, 0, stream>>>(pval, pidx, ids);
    penalty_kernel<<<1, 256, 0, stream>>>(leafsum, out_pen);

    gemm2_log<<<B_ROWS / 32, 256, 0, stream>>>(MU, DT, out_logout);
    gather_logpred<<<B_ROWS, 256, 0, stream>>>(logdist, ids, out_logpred);
    copy_w<<<(NNODES * 513 + 255) / 256, 256, 0, stream>>>(W, out_W);
}

// Round 2
// 512.559 us; speedup vs baseline: 1.2571x; 1.2571x over previous
//
#include <hip/hip_runtime.h>
#include <hip/hip_bf16.h>

#define B_ROWS 16384
#define DDIM   512
#define NNODES 1023
#define NLEAF  1024
#define ODIM   256
#define LAMDA  1e-3
#define EPSV   1e-7f

typedef __bf16 bf16x8v __attribute__((ext_vector_type(8)));
typedef float  f32x16v __attribute__((ext_vector_type(16)));

// ---------------------------------------------------------------------------
// GEMM1: PT[n,b] = sigmoid(beta[n] * (data[b,:] . W[n,1:] + W[n,0]))
// f32 vector SGEMM, 128x128x16 tiles, 256 threads, 8x8 micro-tile.
// Output is TRANSPOSED (node-major) so tree_pass reads are coalesced.
// tx (lane-fast) indexes M so the epilogue writes PT rows as contiguous f32x4.
// ---------------------------------------------------------------------------
#define G1_BM 128
#define G1_BN 128
#define G1_BK 16

__global__ __launch_bounds__(256, 4)
void gemm1_sigmoid(const float* __restrict__ A,    // data [16384,512]
                   const float* __restrict__ W,    // [1023,513]
                   const float* __restrict__ beta, // [1023]
                   float* __restrict__ PT)         // [1023,16384]
{
    __shared__ float As[G1_BK][G1_BM];
    __shared__ float Bs[G1_BK][G1_BN];
    const int tid = threadIdx.x;
    const int m0 = blockIdx.x * G1_BM;
    const int n0 = blockIdx.y * G1_BN;
    const int tx = tid & 15;   // M-fast
    const int ty = tid >> 4;   // N

    float acc[8][8];   // acc[i][j]: i = M index, j = N index
#pragma unroll
    for (int i = 0; i < 8; ++i)
#pragma unroll
        for (int j = 0; j < 8; ++j) acc[i][j] = 0.f;

    const int ar0 = tid >> 2;         // 0..63
    const int ac0 = (tid & 3) << 2;   // 0,4,8,12

    for (int k0 = 0; k0 < DDIM; k0 += G1_BK) {
        // A tile: As[c][r] = A[m0+r][k0+c]
#pragma unroll
        for (int h = 0; h < 2; ++h) {
            int r = ar0 + h * 64;
            const float4 v = *reinterpret_cast<const float4*>(
                &A[(size_t)(m0 + r) * DDIM + k0 + ac0]);
            As[ac0 + 0][r] = v.x;
            As[ac0 + 1][r] = v.y;
            As[ac0 + 2][r] = v.z;
            As[ac0 + 3][r] = v.w;
        }
        // B tile: Bs[c][n] = W[n0+n][k0+c+1]
#pragma unroll
        for (int h = 0; h < 2; ++h) {
            int n = ar0 + h * 64;
            int gn = n0 + n;
            if (gn < NNODES) {
                const float* wr = &W[(size_t)gn * 513 + k0 + 1 + ac0];
#pragma unroll
                for (int jj = 0; jj < 4; ++jj) Bs[ac0 + jj][n] = wr[jj];
            } else {
#pragma unroll
                for (int jj = 0; jj < 4; ++jj) Bs[ac0 + jj][n] = 0.f;
            }
        }
        __syncthreads();
#pragma unroll
        for (int kk = 0; kk < G1_BK; ++kk) {
            float a[8], b[8];
            *reinterpret_cast<float4*>(&a[0]) = *reinterpret_cast<const float4*>(&As[kk][tx * 4]);
            *reinterpret_cast<float4*>(&a[4]) = *reinterpret_cast<const float4*>(&As[kk][tx * 4 + 64]);
            *reinterpret_cast<float4*>(&b[0]) = *reinterpret_cast<const float4*>(&Bs[kk][ty * 4]);
            *reinterpret_cast<float4*>(&b[4]) = *reinterpret_cast<const float4*>(&Bs[kk][ty * 4 + 64]);
#pragma unroll
            for (int i = 0; i < 8; ++i)
#pragma unroll
                for (int j = 0; j < 8; ++j)
                    acc[i][j] = fmaf(a[i], b[j], acc[i][j]);
        }
        __syncthreads();
    }
    // epilogue: bias, beta, sigmoid; write PT[n][m] as contiguous float4 per lane
#pragma unroll
    for (int j = 0; j < 8; ++j) {
        int n = n0 + ty * 4 + (j & 3) + (j >> 2) * 64;
        if (n >= NNODES) continue;
        float w0 = W[(size_t)n * 513];
        float bt = beta[n];
#pragma unroll
        for (int h = 0; h < 2; ++h) {
            float4 v;
            float* vp = &v.x;
#pragma unroll
            for (int q = 0; q < 4; ++q) {
                float s = bt * (acc[h * 4 + q][j] + w0);
                vp[q] = 1.f / (1.f + expf(-s));
            }
            *reinterpret_cast<float4*>(&PT[(size_t)n * B_ROWS + m0 + tx * 4 + h * 64]) = v;
        }
    }
}

// ---------------------------------------------------------------------------
// Tree pass v2: thread = row. All PT loads coalesced (node index is
// block-uniform, lane index = row). No LDS, no __syncthreads.
// Block handles 2 subtree-pairs (4 subtrees = 128 leaves); each pair's 64
// leaves are one contiguous 128B MU line per row -> full-line writes.
// Grid = 64 row-blocks x 8 pair-groups.
// ---------------------------------------------------------------------------
__global__ __launch_bounds__(256, 2)
void tree_pass(const float* __restrict__ PT,      // [1023,16384]
               __hip_bfloat16* __restrict__ MU,   // [16384,1024]
               float* __restrict__ leafsum,       // [1024] (pre-zeroed)
               float* __restrict__ pval,          // [8][16384]
               int*   __restrict__ pidx)          // [8][16384]
{
    const int tid = threadIdx.x;
    const int rb = blockIdx.x & 63;
    const int gg = blockIdx.x >> 6;        // 0..7
    const int b  = rb * 256 + tid;

    float bestv = -1.f;
    int besti = 0;

    for (int pp = 0; pp < 2; ++pp) {
        const int g = gg * 2 + pp;         // pair 0..15 -> leaves g*64..g*64+63
        // ancestor chain of the pair's parent node c4 = 15+g (level 4).
        // 0-based heap: children of i are 2i+1 (prob p) / 2i+2 (prob 1-p).
        const int c4 = 15 + g;
        const int n3 = (c4 - 1) >> 1;
        const int n2 = (n3 - 1) >> 1;
        const int n1 = (n2 - 1) >> 1;
        const float pc4 = PT[(size_t)c4 * B_ROWS + b];
        const float pn3 = PT[(size_t)n3 * B_ROWS + b];
        const float pn2 = PT[(size_t)n2 * B_ROWS + b];
        const float pn1 = PT[(size_t)n1 * B_ROWS + b];
        const float pn0 = PT[b];
        float pre = ((c4 & 1) ? pn3 : 1.f - pn3)
                  * ((n3 & 1) ? pn2 : 1.f - pn2)
                  * ((n2 & 1) ? pn1 : 1.f - pn1)
                  * ((n1 & 1) ? pn0 : 1.f - pn0);
        float root[2];
        root[0] = pre * pc4;          // subtree t = 2g   (left child 31+2g)
        root[1] = pre * (1.f - pc4);  // subtree t = 2g+1 (right child 32+2g)

        __align__(16) __hip_bfloat16 mb[64];

        for (int ss = 0; ss < 2; ++ss) {
            const int t = 2 * g + ss;
            // stage subtree's 31 inner nodes: all loads independent+coalesced
            float s[32];
#pragma unroll
            for (int u = 1; u < 32; ++u) {
                int lvl = 31 - __clz(u);
                int node = ((32 << lvl) - 1) + t * (1 << lvl) + (u - (1 << lvl));
                s[u] = PT[(size_t)node * B_ROWS + b];
            }
            float w[64];
            w[1] = (ss == 0) ? root[0] : root[1];
#pragma unroll
            for (int u = 1; u < 32; ++u) {
                float pu = s[u];
                w[2 * u]     = w[u] * pu;
                w[2 * u + 1] = w[u] * (1.f - pu);
            }
            // leaves: w[32+q] -> global leaf t*32+q
#pragma unroll
            for (int q = 0; q < 32; ++q) {
                float lv = w[32 + q];
                mb[ss * 32 + q] = __float2bfloat16(lv);
                if (lv > bestv) { bestv = lv; besti = t * 32 + q; }
            }
#pragma unroll
            for (int q = 0; q < 32; ++q) {
                float sum = w[32 + q];
#pragma unroll
                for (int m = 1; m < 64; m <<= 1) sum += __shfl_xor(sum, m, 64);
                if ((tid & 63) == 0) atomicAdd(&leafsum[t * 32 + q], sum);
            }
        }
        // 128B contiguous write: full cache lines, no RMW
        {
            const ulonglong2* src = reinterpret_cast<const ulonglong2*>(mb);
            ulonglong2* dst = reinterpret_cast<ulonglong2*>(&MU[(size_t)b * NLEAF + g * 64]);
#pragma unroll
            for (int hh = 0; hh < 8; ++hh) dst[hh] = src[hh];
        }
    }
    pval[(size_t)gg * B_ROWS + b] = bestv;
    pidx[(size_t)gg * B_ROWS + b] = besti;
}

__global__ void argmax_finalize(const float* __restrict__ pval,
                                const int* __restrict__ pidx,
                                int* __restrict__ ids)
{
    int b = blockIdx.x * 256 + threadIdx.x;
    float bv = -1.f; int bi = 0;
    for (int g = 0; g < 8; ++g) {          // ascending g = ascending leaf index
        float v = pval[(size_t)g * B_ROWS + b];
        if (v > bv) { bv = v; bi = pidx[(size_t)g * B_ROWS + b]; }
    }
    ids[b] = bi;
}

// ---------------------------------------------------------------------------
// softmax over param rows -> logdist (f32, for prediction) + distT (bf16, [O][L])
// ---------------------------------------------------------------------------
__global__ __launch_bounds__(256)
void softmax_param(const float* __restrict__ param,   // [1024,256]
                   float* __restrict__ logdist,       // [1024,256]
                   __hip_bfloat16* __restrict__ distT)// [256,1024]
{
    __shared__ float red[4], red2[4];
    int l = blockIdx.x;
    int o = threadIdx.x;
    float x = param[(size_t)l * ODIM + o];
    float m = x;
#pragma unroll
    for (int s = 1; s < 64; s <<= 1) m = fmaxf(m, __shfl_xor(m, s, 64));
    if ((o & 63) == 0) red[o >> 6] = m;
    __syncthreads();
    m = fmaxf(fmaxf(red[0], red[1]), fmaxf(red[2], red[3]));
    float e = expf(x - m);
    float s = e;
#pragma unroll
    for (int k = 1; k < 64; k <<= 1) s += __shfl_xor(s, k, 64);
    if ((o & 63) == 0) red2[o >> 6] = s;
    __syncthreads();
    s = red2[0] + red2[1] + red2[2] + red2[3];
    float d = e / s;
    logdist[(size_t)l * ODIM + o] = logf(d);
    distT[(size_t)o * NLEAF + l] = __float2bfloat16(d);
}

// ---------------------------------------------------------------------------
// penalty: heap-aggregate leaf colsums, sum log(alpha)+log(1-alpha) terms.
// ---------------------------------------------------------------------------
__global__ __launch_bounds__(256)
void penalty_kernel(const float* __restrict__ leafsum, float* __restrict__ out_pen)
{
    __shared__ float M[2048];
    __shared__ double dred[256];
    int tid = threadIdx.x;
    for (int i = tid; i < 1024; i += 256) M[1024 + i] = leafsum[i];
    __syncthreads();
    for (int n = 512; n >= 1; n >>= 1) {
        for (int u = n + tid; u < 2 * n; u += 256) M[u] = M[2 * u] + M[2 * u + 1];
        __syncthreads();
    }
    double acc = 0.0;
    for (int u = 2 + tid; u < 2048; u += 256) {
        int lvl = 31 - __clz(u);                    // 1..10 == layer+1
        float a = M[u] / (M[u >> 1] + EPSV);
        a = fminf(fmaxf(a, EPSV), 1.f - EPSV);
        float term = logf(a) + logf(1.f - a);
        acc -= ldexp((double)LAMDA * 0.5, 1 - lvl) * (double)term;
    }
    dred[tid] = acc;
    __syncthreads();
    for (int s = 128; s > 0; s >>= 1) {
        if (tid < s) dred[tid] += dred[tid + s];
        __syncthreads();
    }
    if (tid == 0) out_pen[0] = (float)dred[0];
}

// ---------------------------------------------------------------------------
// GEMM2: out1 = log(mu @ dist) via bf16 MFMA 32x32x16.
// ---------------------------------------------------------------------------
__global__ __launch_bounds__(256)
void gemm2_log(const __hip_bfloat16* __restrict__ MU,  // [16384,1024]
               const __hip_bfloat16* __restrict__ DT,  // [256,1024]
               float* __restrict__ out1)               // [16384,256]
{
    __shared__ __align__(16) __hip_bfloat16 ldsB[256][40]; // [n][k], +8 pad
    __shared__ __align__(16) __hip_bfloat16 ldsA[32][40];  // [m][k], +8 pad
    const int tid = threadIdx.x;
    const int lane = tid & 63;
    const int wv = tid >> 6;
    const int m0 = blockIdx.x * 32;
    const int n0w = wv * 64;
    const int lr = lane & 31;
    const int lh = lane >> 5;

    f32x16v acc0 = {}; f32x16v acc1 = {};

    for (int k0 = 0; k0 < NLEAF; k0 += 32) {
        __syncthreads();
        {   // stage B slice: DT[n=tid][k0..k0+31]
            const ulonglong2* src = reinterpret_cast<const ulonglong2*>(&DT[(size_t)tid * NLEAF + k0]);
            ulonglong2* dst = reinterpret_cast<ulonglong2*>(&ldsB[tid][0]);
#pragma unroll
            for (int h = 0; h < 4; ++h) dst[h] = src[h];
        }
        if (tid < 128) {  // stage A slice: MU[m0+r][k0..k0+31]
            int r = tid >> 2, cc = (tid & 3) * 8;
            *reinterpret_cast<ulonglong2*>(&ldsA[r][cc]) =
                *reinterpret_cast<const ulonglong2*>(&MU[(size_t)(m0 + r) * NLEAF + k0 + cc]);
        }
        __syncthreads();
        bf16x8v a0 = *reinterpret_cast<const bf16x8v*>(&ldsA[lr][lh * 8]);
        bf16x8v a1 = *reinterpret_cast<const bf16x8v*>(&ldsA[lr][16 + lh * 8]);
        bf16x8v b00 = *reinterpret_cast<const bf16x8v*>(&ldsB[n0w + lr][lh * 8]);
        bf16x8v b01 = *reinterpret_cast<const bf16x8v*>(&ldsB[n0w + lr][16 + lh * 8]);
        bf16x8v b10 = *reinterpret_cast<const bf16x8v*>(&ldsB[n0w + 32 + lr][lh * 8]);
        bf16x8v b11 = *reinterpret_cast<const bf16x8v*>(&ldsB[n0w + 32 + lr][16 + lh * 8]);
        acc0 = __builtin_amdgcn_mfma_f32_32x32x16_bf16(a0, b00, acc0, 0, 0, 0);
        acc0 = __builtin_amdgcn_mfma_f32_32x32x16_bf16(a1, b01, acc0, 0, 0, 0);
        acc1 = __builtin_amdgcn_mfma_f32_32x32x16_bf16(a0, b10, acc1, 0, 0, 0);
        acc1 = __builtin_amdgcn_mfma_f32_32x32x16_bf16(a1, b11, acc1, 0, 0, 0);
    }
    // D layout: col = lane&31, row = (reg&3) + 8*(reg>>2) + 4*(lane>>5)
#pragma unroll
    for (int r = 0; r < 16; ++r) {
        int row = (r & 3) + 8 * (r >> 2) + 4 * lh;
        size_t base = (size_t)(m0 + row) * ODIM + n0w + lr;
        out1[base]      = logf(acc0[r]);
        out1[base + 32] = logf(acc1[r]);
    }
}

__global__ void gather_logpred(const float* __restrict__ logdist,
                               const int* __restrict__ ids,
                               float* __restrict__ out0)
{
    int b = blockIdx.x;
    int o = threadIdx.x;
    int id = ids[b];
    out0[(size_t)b * ODIM + o] = logdist[(size_t)id * ODIM + o];
}

__global__ void copy_w(const float* __restrict__ W, float* __restrict__ outW)
{
    int i = blockIdx.x * 256 + threadIdx.x;
    if (i < NNODES * 513) outW[i] = W[i];
}

// ---------------------------------------------------------------------------
extern "C" void kernel_launch(void* const* d_in, const int* in_sizes, int n_in,
                              void* d_out, int out_size, void* d_ws, size_t ws_size,
                              hipStream_t stream)
{
    (void)in_sizes; (void)n_in; (void)out_size; (void)ws_size;
    const float* data  = (const float*)d_in[0];
    const float* W     = (const float*)d_in[1];
    const float* beta  = (const float*)d_in[2];
    const float* param = (const float*)d_in[3];
    float* out = (float*)d_out;

    char* ws = (char*)d_ws;
    size_t off = 0;
    float* PT = (float*)(ws + off);              off += (size_t)NNODES * B_ROWS * 4;
    __hip_bfloat16* MU = (__hip_bfloat16*)(ws + off); off += (size_t)B_ROWS * NLEAF * 2;
    __hip_bfloat16* DT = (__hip_bfloat16*)(ws + off); off += (size_t)ODIM * NLEAF * 2;
    float* logdist = (float*)(ws + off);         off += (size_t)NLEAF * ODIM * 4;
    int*   ids     = (int*)(ws + off);           off += (size_t)B_ROWS * 4;
    float* leafsum = (float*)(ws + off);         off += (size_t)NLEAF * 4;
    float* pval    = (float*)(ws + off);         off += (size_t)8 * B_ROWS * 4;
    int*   pidx    = (int*)(ws + off);           off += (size_t)8 * B_ROWS * 4;
    // total ws use: ~103.3 MB (same as previous passing version)

    float* out_logpred = out;
    float* out_logout  = out + (size_t)B_ROWS * ODIM;
    float* out_pen     = out + 2 * (size_t)B_ROWS * ODIM;
    float* out_W       = out_pen + 1;

    hipMemsetAsync(leafsum, 0, NLEAF * 4, stream);

    softmax_param<<<NLEAF, 256, 0, stream>>>(param, logdist, DT);

    dim3 g1grid(B_ROWS / G1_BM, (NNODES + G1_BN - 1) / G1_BN);
    gemm1_sigmoid<<<g1grid, 256, 0, stream>>>(data, W, beta, PT);

    tree_pass<<<512, 256, 0, stream>>>(PT, MU, leafsum, pval, pidx);
    argmax_finalize<<<B_ROWS / 256, 256, 0, stream>>>(pval, pidx, ids);
    penalty_kernel<<<1, 256, 0, stream>>>(leafsum, out_pen);

    gemm2_log<<<B_ROWS / 32, 256, 0, stream>>>(MU, DT, out_logout);
    gather_logpred<<<B_ROWS, 256, 0, stream>>>(logdist, ids, out_logpred);
    copy_w<<<(NNODES * 513 + 255) / 256, 256, 0, stream>>>(W, out_W);
}

// Round 3
// 212.816 us; speedup vs baseline: 3.0276x; 2.4085x over previous
//
#include <hip/hip_runtime.h>
#include <hip/hip_bf16.h>

#define B_ROWS 16384
#define DDIM   512
#define NNODES 1023
#define NLEAF  1024
#define ODIM   256
#define LAMDA  1e-3
#define EPSV   1e-7f

typedef __bf16 bf16x8v __attribute__((ext_vector_type(8)));
typedef _Float16 f16x8 __attribute__((ext_vector_type(8)));
typedef float  f32x16v __attribute__((ext_vector_type(16)));

__device__ __forceinline__ float bf2f(unsigned short u) {
    return __uint_as_float(((unsigned)u) << 16);
}

// async global->LDS 16B copy (dst must be linear: wave-uniform base + lane*16)
__device__ __forceinline__ void gload16(const _Float16* g, _Float16* l) {
    __builtin_amdgcn_global_load_lds(
        (const __attribute__((address_space(1))) unsigned int*)g,
        (__attribute__((address_space(3))) unsigned int*)l, 16, 0, 0);
}

// ---------------------------------------------------------------------------
// prep_data: data[16384][512] f32 -> Dh,Dl fp16 in MFMA-fragment-tiled order:
// layout [by(128)][ks(32)][tile(4)][lane(64)][8]; lane = (b&31) | ((khalf)<<5)
// Split: a = ah + al/2048 (al pre-scaled by 2048 to stay in fp16 normal range).
// ---------------------------------------------------------------------------
__global__ __launch_bounds__(256)
void prep_data(const float* __restrict__ data,
               _Float16* __restrict__ Dh, _Float16* __restrict__ Dl)
{
    int idx = blockIdx.x * 256 + threadIdx.x;   // 1,048,576 threads
    int b  = idx >> 6;
    int k8 = idx & 63;
    const float4 v0 = *reinterpret_cast<const float4*>(&data[(size_t)b * DDIM + k8 * 8]);
    const float4 v1 = *reinterpret_cast<const float4*>(&data[(size_t)b * DDIM + k8 * 8 + 4]);
    float a[8] = {v0.x, v0.y, v0.z, v0.w, v1.x, v1.y, v1.z, v1.w};
    __align__(16) _Float16 h[8], l[8];
#pragma unroll
    for (int j = 0; j < 8; ++j) {
        h[j] = (_Float16)a[j];
        l[j] = (_Float16)((a[j] - (float)h[j]) * 2048.f);
    }
    int by = b >> 7, tl = (b >> 5) & 3, ln = (b & 31) | ((k8 & 1) << 5), ks = k8 >> 1;
    size_t off = ((((size_t)by * 32 + ks) * 4 + tl) * 64 + ln) * 8;
    *reinterpret_cast<ulonglong2*>(&Dh[off]) = *reinterpret_cast<const ulonglong2*>(h);
    *reinterpret_cast<ulonglong2*>(&Dl[off]) = *reinterpret_cast<const ulonglong2*>(l);
}

// ---------------------------------------------------------------------------
// prep_w: W[1023][513] (cols 1..512) -> Wh,Wl fp16 tiled [nb(8)][ks(32)][tm(4)][64][8]
// node 1023 padded with zeros.
// ---------------------------------------------------------------------------
__global__ __launch_bounds__(256)
void prep_w(const float* __restrict__ W,
            _Float16* __restrict__ Wh, _Float16* __restrict__ Wl)
{
    int idx = blockIdx.x * 256 + threadIdx.x;   // 65536 threads
    int t  = idx & 255;
    int ks = (idx >> 8) & 31;
    int nb = idx >> 13;
    int tm = t >> 6, ln = t & 63;
    int node = nb * 128 + tm * 32 + (ln & 31);
    int k = ks * 16 + (ln >> 5) * 8;
    __align__(16) _Float16 h[8], l[8];
    if (node < NNODES) {
#pragma unroll
        for (int j = 0; j < 8; ++j) {
            float a = W[(size_t)node * 513 + 1 + k + j];
            h[j] = (_Float16)a;
            l[j] = (_Float16)((a - (float)h[j]) * 2048.f);
        }
    } else {
#pragma unroll
        for (int j = 0; j < 8; ++j) { h[j] = (_Float16)0.f; l[j] = (_Float16)0.f; }
    }
    size_t off = (size_t)idx * 8;
    *reinterpret_cast<ulonglong2*>(&Wh[off]) = *reinterpret_cast<const ulonglong2*>(h);
    *reinterpret_cast<ulonglong2*>(&Wl[off]) = *reinterpret_cast<const ulonglong2*>(l);
}

// ---------------------------------------------------------------------------
// GEMM1 via fp16-split MFMA: z = W.data (f32-accurate), p = sigmoid(beta(z+w0))
// -> PT[1023][16384]. Block = 128 nodes x 128 batch, 4 waves (2x2 quadrants),
// 2-phase global_load_lds pipeline, fragment-ordered LDS (conflict-free).
// z = acc_h + acc_l/2048  (acc_l holds ah*bl' + al'*bh, lo pre-scaled 2048).
// ---------------------------------------------------------------------------
__global__ __launch_bounds__(256, 2)
void gemm1_mfma(const _Float16* __restrict__ Wh, const _Float16* __restrict__ Wl,
                const _Float16* __restrict__ Dh, const _Float16* __restrict__ Dl,
                const float* __restrict__ W, const float* __restrict__ beta,
                float* __restrict__ PT)
{
    __shared__ _Float16 lds[2][4][2048];   // [buf][Wh,Wl,Dh,Dl][4KB]
    const int tid = threadIdx.x;
    const int lane = tid & 63;
    const int wv = tid >> 6;
    const int wm = wv & 1, wn = wv >> 1;
    // XCD-bijective swizzle: all 8 node-blocks of one batch-tile on one XCD
    const int id = blockIdx.x;
    const int xcd = id & 7, slot = id >> 3;
    const int bx = slot & 7;                 // node block (128 nodes)
    const int by = xcd * 16 + (slot >> 3);   // batch block (128 batches)
    const size_t wofs = (size_t)bx * 65536 + tid * 8;
    const size_t dofs = (size_t)by * 65536 + tid * 8;
    const int t16 = tid * 8;

    f32x16v acc_h[2][2] = {};
    f32x16v acc_l[2][2] = {};

    // prologue: stage ks=0 into buf0
    gload16(Wh + wofs, &lds[0][0][t16]);
    gload16(Wl + wofs, &lds[0][1][t16]);
    gload16(Dh + dofs, &lds[0][2][t16]);
    gload16(Dl + dofs, &lds[0][3][t16]);

    for (int ks = 0; ks < 32; ++ks) {
        const int cur = ks & 1;
        if (ks + 1 < 32) {
            const size_t so = (size_t)(ks + 1) * 2048;
            gload16(Wh + wofs + so, &lds[cur ^ 1][0][t16]);
            gload16(Wl + wofs + so, &lds[cur ^ 1][1][t16]);
            gload16(Dh + dofs + so, &lds[cur ^ 1][2][t16]);
            gload16(Dl + dofs + so, &lds[cur ^ 1][3][t16]);
            asm volatile("s_waitcnt vmcnt(4)" ::: "memory");
        } else {
            asm volatile("s_waitcnt vmcnt(0)" ::: "memory");
        }
        __syncthreads();
        f16x8 ah[2], al[2], bh[2], bl[2];
#pragma unroll
        for (int i = 0; i < 2; ++i) {
            ah[i] = *reinterpret_cast<const f16x8*>(&lds[cur][0][(wm * 2 + i) * 512 + lane * 8]);
            al[i] = *reinterpret_cast<const f16x8*>(&lds[cur][1][(wm * 2 + i) * 512 + lane * 8]);
            bh[i] = *reinterpret_cast<const f16x8*>(&lds[cur][2][(wn * 2 + i) * 512 + lane * 8]);
            bl[i] = *reinterpret_cast<const f16x8*>(&lds[cur][3][(wn * 2 + i) * 512 + lane * 8]);
        }
#pragma unroll
        for (int i = 0; i < 2; ++i)
#pragma unroll
            for (int j = 0; j < 2; ++j) {
                acc_h[i][j] = __builtin_amdgcn_mfma_f32_32x32x16_f16(ah[i], bh[j], acc_h[i][j], 0, 0, 0);
                acc_l[i][j] = __builtin_amdgcn_mfma_f32_32x32x16_f16(ah[i], bl[j], acc_l[i][j], 0, 0, 0);
                acc_l[i][j] = __builtin_amdgcn_mfma_f32_32x32x16_f16(al[i], bh[j], acc_l[i][j], 0, 0, 0);
            }
        __syncthreads();
    }
    // epilogue: z -> sigmoid -> PT[node][b]  (col=lane&31 -> batch: coalesced)
#pragma unroll
    for (int i = 0; i < 2; ++i) {
#pragma unroll
        for (int r = 0; r < 16; ++r) {
            int node = bx * 128 + wm * 64 + i * 32 + ((r & 3) + 8 * (r >> 2) + 4 * (lane >> 5));
            if (node < NNODES) {
                float w0 = W[(size_t)node * 513];
                float bt = beta[node];
#pragma unroll
                for (int j = 0; j < 2; ++j) {
                    float z = acc_h[i][j][r] + acc_l[i][j][r] * 4.8828125e-4f;
                    float s = bt * (z + w0);
                    float p = 1.f / (1.f + expf(-s));
                    PT[(size_t)node * B_ROWS + by * 128 + wn * 64 + j * 32 + (lane & 31)] = p;
                }
            }
        }
    }
}

// ---------------------------------------------------------------------------
// Tree pass v3: thread = row, one subtree-pair per block. No LDS/barriers/
// atomics; 67 independent coalesced loads per thread. Grid 1024 blocks.
// ---------------------------------------------------------------------------
__global__ __launch_bounds__(256, 4)
void tree_pass(const float* __restrict__ PT,      // [1023,16384]
               __hip_bfloat16* __restrict__ MU,   // [16384,1024]
               float* __restrict__ pval,          // [16][16384]
               int*   __restrict__ pidx)          // [16][16384]
{
    const int tid = threadIdx.x;
    const int rb = blockIdx.x & 63;
    const int g  = blockIdx.x >> 6;        // pair 0..15
    const int b  = rb * 256 + tid;

    const int c4 = 15 + g;
    const int n3 = (c4 - 1) >> 1;
    const int n2 = (n3 - 1) >> 1;
    const int n1 = (n2 - 1) >> 1;
    const float pc4 = PT[(size_t)c4 * B_ROWS + b];
    const float pn3 = PT[(size_t)n3 * B_ROWS + b];
    const float pn2 = PT[(size_t)n2 * B_ROWS + b];
    const float pn1 = PT[(size_t)n1 * B_ROWS + b];
    const float pn0 = PT[b];
    float pre = ((c4 & 1) ? pn3 : 1.f - pn3)
              * ((n3 & 1) ? pn2 : 1.f - pn2)
              * ((n2 & 1) ? pn1 : 1.f - pn1)
              * ((n1 & 1) ? pn0 : 1.f - pn0);
    float root[2] = { pre * pc4, pre * (1.f - pc4) };

    float bestv = -1.f; int besti = 0;
#pragma unroll
    for (int ss = 0; ss < 2; ++ss) {
        const int t = 2 * g + ss;
        float s[32];
#pragma unroll
        for (int u = 1; u < 32; ++u) {
            int lvl = 31 - __clz(u);
            int node = ((32 << lvl) - 1) + t * (1 << lvl) + (u - (1 << lvl));
            s[u] = PT[(size_t)node * B_ROWS + b];
        }
        float w[64];
        w[1] = root[ss];
#pragma unroll
        for (int u = 1; u < 32; ++u) {
            w[2 * u]     = w[u] * s[u];
            w[2 * u + 1] = w[u] * (1.f - s[u]);
        }
        __align__(16) __hip_bfloat16 mb[32];
#pragma unroll
        for (int q = 0; q < 32; ++q) {
            float lv = w[32 + q];
            mb[q] = __float2bfloat16(lv);
            if (lv > bestv) { bestv = lv; besti = t * 32 + q; }
        }
        // 64B aligned contiguous store per thread = full sectors
        ulonglong2* dst = reinterpret_cast<ulonglong2*>(&MU[(size_t)b * NLEAF + t * 32]);
        const ulonglong2* src = reinterpret_cast<const ulonglong2*>(mb);
#pragma unroll
        for (int hh = 0; hh < 4; ++hh) dst[hh] = src[hh];
    }
    pval[(size_t)g * B_ROWS + b] = bestv;
    pidx[(size_t)g * B_ROWS + b] = besti;
}

__global__ void argmax_finalize(const float* __restrict__ pval,
                                const int* __restrict__ pidx,
                                int* __restrict__ ids)
{
    int b = blockIdx.x * 256 + threadIdx.x;
    float bv = -1.f; int bi = 0;
    for (int g = 0; g < 16; ++g) {         // ascending g = ascending leaf index
        float v = pval[(size_t)g * B_ROWS + b];
        if (v > bv) { bv = v; bi = pidx[(size_t)g * B_ROWS + b]; }
    }
    ids[b] = bi;
}

// ---------------------------------------------------------------------------
// colsum: leaf column sums from bf16 MU. 128 blocks x 128 rows, coalesced.
// ---------------------------------------------------------------------------
__global__ __launch_bounds__(256)
void colsum(const __hip_bfloat16* __restrict__ MU, float* __restrict__ partial)
{
    const int tid = threadIdx.x;
    const int blk = blockIdx.x;            // 128 blocks
    float a0 = 0.f, a1 = 0.f, a2 = 0.f, a3 = 0.f;
    for (int r = 0; r < 128; ++r) {
        size_t row = (size_t)blk * 128 + r;
        ushort4 v = *reinterpret_cast<const ushort4*>(
            reinterpret_cast<const unsigned short*>(MU) + row * NLEAF + tid * 4);
        a0 += bf2f(v.x); a1 += bf2f(v.y); a2 += bf2f(v.z); a3 += bf2f(v.w);
    }
    float4 o = {a0, a1, a2, a3};
    *reinterpret_cast<float4*>(&partial[(size_t)blk * NLEAF + tid * 4]) = o;
}

// ---------------------------------------------------------------------------
// softmax over param rows -> logdist (f32) + distT (bf16, [O][L])
// ---------------------------------------------------------------------------
__global__ __launch_bounds__(256)
void softmax_param(const float* __restrict__ param,
                   float* __restrict__ logdist,
                   __hip_bfloat16* __restrict__ distT)
{
    __shared__ float red[4], red2[4];
    int l = blockIdx.x;
    int o = threadIdx.x;
    float x = param[(size_t)l * ODIM + o];
    float m = x;
#pragma unroll
    for (int s = 1; s < 64; s <<= 1) m = fmaxf(m, __shfl_xor(m, s, 64));
    if ((o & 63) == 0) red[o >> 6] = m;
    __syncthreads();
    m = fmaxf(fmaxf(red[0], red[1]), fmaxf(red[2], red[3]));
    float e = expf(x - m);
    float s = e;
#pragma unroll
    for (int k = 1; k < 64; k <<= 1) s += __shfl_xor(s, k, 64);
    if ((o & 63) == 0) red2[o >> 6] = s;
    __syncthreads();
    s = red2[0] + red2[1] + red2[2] + red2[3];
    float d = e / s;
    logdist[(size_t)l * ODIM + o] = logf(d);
    distT[(size_t)o * NLEAF + l] = __float2bfloat16(d);
}

// ---------------------------------------------------------------------------
// penalty: reduce partial colsums, heap-aggregate, sum log terms.
// ---------------------------------------------------------------------------
__global__ __launch_bounds__(256)
void penalty_kernel(const float* __restrict__ partial, float* __restrict__ out_pen)
{
    __shared__ float M[2048];
    __shared__ double dred[256];
    int tid = threadIdx.x;
    for (int i = tid; i < 1024; i += 256) {
        float s = 0.f;
        for (int r = 0; r < 128; ++r) s += partial[(size_t)r * NLEAF + i];
        M[1024 + i] = s;
    }
    __syncthreads();
    for (int n = 512; n >= 1; n >>= 1) {
        for (int u = n + tid; u < 2 * n; u += 256) M[u] = M[2 * u] + M[2 * u + 1];
        __syncthreads();
    }
    double acc = 0.0;
    for (int u = 2 + tid; u < 2048; u += 256) {
        int lvl = 31 - __clz(u);                    // 1..10 == layer+1
        float a = M[u] / (M[u >> 1] + EPSV);
        a = fminf(fmaxf(a, EPSV), 1.f - EPSV);
        float term = logf(a) + logf(1.f - a);
        acc -= ldexp((double)LAMDA * 0.5, 1 - lvl) * (double)term;
    }
    dred[tid] = acc;
    __syncthreads();
    for (int s = 128; s > 0; s >>= 1) {
        if (tid < s) dred[tid] += dred[tid + s];
        __syncthreads();
    }
    if (tid == 0) out_pen[0] = (float)dred[0];
}

// ---------------------------------------------------------------------------
// GEMM2: out1 = log(mu @ dist) via bf16 MFMA 32x32x16.
// ---------------------------------------------------------------------------
__global__ __launch_bounds__(256)
void gemm2_log(const __hip_bfloat16* __restrict__ MU,  // [16384,1024]
               const __hip_bfloat16* __restrict__ DT,  // [256,1024]
               float* __restrict__ out1)               // [16384,256]
{
    __shared__ __align__(16) __hip_bfloat16 ldsB[256][40];
    __shared__ __align__(16) __hip_bfloat16 ldsA[32][40];
    const int tid = threadIdx.x;
    const int lane = tid & 63;
    const int wv = tid >> 6;
    const int m0 = blockIdx.x * 32;
    const int n0w = wv * 64;
    const int lr = lane & 31;
    const int lh = lane >> 5;

    f32x16v acc0 = {}; f32x16v acc1 = {};

    for (int k0 = 0; k0 < NLEAF; k0 += 32) {
        __syncthreads();
        {
            const ulonglong2* src = reinterpret_cast<const ulonglong2*>(&DT[(size_t)tid * NLEAF + k0]);
            ulonglong2* dst = reinterpret_cast<ulonglong2*>(&ldsB[tid][0]);
#pragma unroll
            for (int h = 0; h < 4; ++h) dst[h] = src[h];
        }
        if (tid < 128) {
            int r = tid >> 2, cc = (tid & 3) * 8;
            *reinterpret_cast<ulonglong2*>(&ldsA[r][cc]) =
                *reinterpret_cast<const ulonglong2*>(&MU[(size_t)(m0 + r) * NLEAF + k0 + cc]);
        }
        __syncthreads();
        bf16x8v a0 = *reinterpret_cast<const bf16x8v*>(&ldsA[lr][lh * 8]);
        bf16x8v a1 = *reinterpret_cast<const bf16x8v*>(&ldsA[lr][16 + lh * 8]);
        bf16x8v b00 = *reinterpret_cast<const bf16x8v*>(&ldsB[n0w + lr][lh * 8]);
        bf16x8v b01 = *reinterpret_cast<const bf16x8v*>(&ldsB[n0w + lr][16 + lh * 8]);
        bf16x8v b10 = *reinterpret_cast<const bf16x8v*>(&ldsB[n0w + 32 + lr][lh * 8]);
        bf16x8v b11 = *reinterpret_cast<const bf16x8v*>(&ldsB[n0w + 32 + lr][16 + lh * 8]);
        acc0 = __builtin_amdgcn_mfma_f32_32x32x16_bf16(a0, b00, acc0, 0, 0, 0);
        acc0 = __builtin_amdgcn_mfma_f32_32x32x16_bf16(a1, b01, acc0, 0, 0, 0);
        acc1 = __builtin_amdgcn_mfma_f32_32x32x16_bf16(a0, b10, acc1, 0, 0, 0);
        acc1 = __builtin_amdgcn_mfma_f32_32x32x16_bf16(a1, b11, acc1, 0, 0, 0);
    }
#pragma unroll
    for (int r = 0; r < 16; ++r) {
        int row = (r & 3) + 8 * (r >> 2) + 4 * lh;
        size_t base = (size_t)(m0 + row) * ODIM + n0w + lr;
        out1[base]      = logf(acc0[r]);
        out1[base + 32] = logf(acc1[r]);
    }
}

__global__ void gather_logpred(const float* __restrict__ logdist,
                               const int* __restrict__ ids,
                               float* __restrict__ out0)
{
    int b = blockIdx.x;
    int o = threadIdx.x;
    int id = ids[b];
    out0[(size_t)b * ODIM + o] = logdist[(size_t)id * ODIM + o];
}

__global__ void copy_w(const float* __restrict__ W, float* __restrict__ outW)
{
    int i = blockIdx.x * 256 + threadIdx.x;
    if (i < NNODES * 513) outW[i] = W[i];
}

// ---------------------------------------------------------------------------
extern "C" void kernel_launch(void* const* d_in, const int* in_sizes, int n_in,
                              void* d_out, int out_size, void* d_ws, size_t ws_size,
                              hipStream_t stream)
{
    (void)in_sizes; (void)n_in; (void)out_size; (void)ws_size;
    const float* data  = (const float*)d_in[0];
    const float* W     = (const float*)d_in[1];
    const float* beta  = (const float*)d_in[2];
    const float* param = (const float*)d_in[3];
    float* out = (float*)d_out;

    char* ws = (char*)d_ws;
    size_t off = 0;
    float* PT = (float*)(ws + off);                   off += (size_t)NNODES * B_ROWS * 4;   // 67.04 MB
    // X region: Wh,Wl,Dh,Dl live prep->gemm1; MU (overlay on Dh+Dl) live after
    char* X = ws + off;                               off += 2 * 1048576 + 2 * 16777216;    // 35.65 MB
    _Float16* Wh = (_Float16*)(X);
    _Float16* Wl = (_Float16*)(X + 1048576);
    _Float16* Dh = (_Float16*)(X + 2 * 1048576);
    _Float16* Dl = (_Float16*)(X + 2 * 1048576 + 16777216);
    __hip_bfloat16* MU = (__hip_bfloat16*)(X + 2 * 1048576);  // 33.55 MB == Dh+Dl exactly
    __hip_bfloat16* DT = (__hip_bfloat16*)(ws + off); off += (size_t)ODIM * NLEAF * 2;
    float* logdist = (float*)(ws + off);              off += (size_t)NLEAF * ODIM * 4;
    int*   ids     = (int*)(ws + off);                off += (size_t)B_ROWS * 4;
    float* partial = (float*)(ws + off);              off += (size_t)128 * NLEAF * 4;
    float* pval    = (float*)(ws + off);              off += (size_t)16 * B_ROWS * 4;
    int*   pidx    = (int*)(ws + off);                off += (size_t)16 * B_ROWS * 4;
    // total ~107 MB

    float* out_logpred = out;
    float* out_logout  = out + (size_t)B_ROWS * ODIM;
    float* out_pen     = out + 2 * (size_t)B_ROWS * ODIM;
    float* out_W       = out_pen + 1;

    prep_data<<<4096, 256, 0, stream>>>(data, Dh, Dl);
    prep_w<<<256, 256, 0, stream>>>(W, Wh, Wl);
    softmax_param<<<NLEAF, 256, 0, stream>>>(param, logdist, DT);

    gemm1_mfma<<<1024, 256, 0, stream>>>(Wh, Wl, Dh, Dl, W, beta, PT);

    tree_pass<<<1024, 256, 0, stream>>>(PT, MU, pval, pidx);
    argmax_finalize<<<B_ROWS / 256, 256, 0, stream>>>(pval, pidx, ids);
    colsum<<<128, 256, 0, stream>>>(MU, partial);
    penalty_kernel<<<1, 256, 0, stream>>>(partial, out_pen);

    gemm2_log<<<B_ROWS / 32, 256, 0, stream>>>(MU, DT, out_logout);
    gather_logpred<<<B_ROWS, 256, 0, stream>>>(logdist, ids, out_logpred);
    copy_w<<<(NNODES * 513 + 255) / 256, 256, 0, stream>>>(W, out_W);
}

// Round 5
// 162.751 us; speedup vs baseline: 3.9589x; 1.3076x over previous
//
#include <hip/hip_runtime.h>
#include <hip/hip_bf16.h>

#define B_ROWS 16384
#define DDIM   512
#define NNODES 1023
#define NLEAF  1024
#define ODIM   256
#define LAMDA  1e-3
#define EPSV   1e-7f

typedef __bf16 bf16x8v __attribute__((ext_vector_type(8)));
typedef _Float16 f16x8 __attribute__((ext_vector_type(8)));
typedef float  f32x16v __attribute__((ext_vector_type(16)));

__device__ __forceinline__ float bf2f(unsigned short u) {
    return __uint_as_float(((unsigned)u) << 16);
}

// async global->LDS 16B copy (dst linear: wave-uniform base + lane*16)
__device__ __forceinline__ void gload16h(const _Float16* g, _Float16* l) {
    __builtin_amdgcn_global_load_lds(
        (const __attribute__((address_space(1))) unsigned int*)g,
        (__attribute__((address_space(3))) unsigned int*)l, 16, 0, 0);
}
__device__ __forceinline__ void gload16b(const __hip_bfloat16* g, __hip_bfloat16* l) {
    __builtin_amdgcn_global_load_lds(
        (const __attribute__((address_space(1))) unsigned int*)g,
        (__attribute__((address_space(3))) unsigned int*)l, 16, 0, 0);
}

// ---------------------------------------------------------------------------
// prep_data: data f32 -> Dh,Dl fp16, MFMA-fragment-tiled
// [by(128)][ks(32)][tl(4)][lane(64)][8]; row=by*128+tl*32+(ln&31), k=ks*16+(ln>>5)*8+j
// ---------------------------------------------------------------------------
__global__ __launch_bounds__(256)
void prep_data(const float* __restrict__ data,
               _Float16* __restrict__ Dh, _Float16* __restrict__ Dl)
{
    int idx = blockIdx.x * 256 + threadIdx.x;
    int b  = idx >> 6;
    int k8 = idx & 63;
    const float4 v0 = *reinterpret_cast<const float4*>(&data[(size_t)b * DDIM + k8 * 8]);
    const float4 v1 = *reinterpret_cast<const float4*>(&data[(size_t)b * DDIM + k8 * 8 + 4]);
    float a[8] = {v0.x, v0.y, v0.z, v0.w, v1.x, v1.y, v1.z, v1.w};
    __align__(16) _Float16 h[8], l[8];
#pragma unroll
    for (int j = 0; j < 8; ++j) {
        h[j] = (_Float16)a[j];
        l[j] = (_Float16)((a[j] - (float)h[j]) * 2048.f);
    }
    int by = b >> 7, tl = (b >> 5) & 3, ln = (b & 31) | ((k8 & 1) << 5), ks = k8 >> 1;
    size_t off = ((((size_t)by * 32 + ks) * 4 + tl) * 64 + ln) * 8;
    *reinterpret_cast<ulonglong2*>(&Dh[off]) = *reinterpret_cast<const ulonglong2*>(h);
    *reinterpret_cast<ulonglong2*>(&Dl[off]) = *reinterpret_cast<const ulonglong2*>(l);
}

// ---------------------------------------------------------------------------
// prep_w: W cols 1..512 -> Wh,Wl fp16 tiled [nb(8)][ks(32)][tm(4)][64][8]
// ---------------------------------------------------------------------------
__global__ __launch_bounds__(256)
void prep_w(const float* __restrict__ W,
            _Float16* __restrict__ Wh, _Float16* __restrict__ Wl)
{
    int idx = blockIdx.x * 256 + threadIdx.x;
    int t  = idx & 255;
    int ks = (idx >> 8) & 31;
    int nb = idx >> 13;
    int tm = t >> 6, ln = t & 63;
    int node = nb * 128 + tm * 32 + (ln & 31);
    int k = ks * 16 + (ln >> 5) * 8;
    __align__(16) _Float16 h[8], l[8];
    if (node < NNODES) {
#pragma unroll
        for (int j = 0; j < 8; ++j) {
            float a = W[(size_t)node * 513 + 1 + k + j];
            h[j] = (_Float16)a;
            l[j] = (_Float16)((a - (float)h[j]) * 2048.f);
        }
    } else {
#pragma unroll
        for (int j = 0; j < 8; ++j) { h[j] = (_Float16)0.f; l[j] = (_Float16)0.f; }
    }
    size_t off = (size_t)idx * 8;
    *reinterpret_cast<ulonglong2*>(&Wh[off]) = *reinterpret_cast<const ulonglong2*>(h);
    *reinterpret_cast<ulonglong2*>(&Wl[off]) = *reinterpret_cast<const ulonglong2*>(l);
}

// ---------------------------------------------------------------------------
// GEMM1 fp16-split MFMA, BK=32, raw barriers + counted vmcnt + setprio.
// ---------------------------------------------------------------------------
__global__ __launch_bounds__(256, 2)
void gemm1_mfma(const _Float16* __restrict__ Wh, const _Float16* __restrict__ Wl,
                const _Float16* __restrict__ Dh, const _Float16* __restrict__ Dl,
                const float* __restrict__ W, const float* __restrict__ beta,
                float* __restrict__ PT)
{
    __shared__ _Float16 lds[2][4][4096];   // 64KB: [buf][Wh,Wl,Dh,Dl][BK=32 chunk]
    const int tid = threadIdx.x;
    const int lane = tid & 63;
    const int wv = tid >> 6;
    const int wm = wv & 1, wn = wv >> 1;
    const int id = blockIdx.x;
    const int xcd = id & 7, slot = id >> 3;
    const int bx = slot & 7;
    const int by = xcd * 16 + (slot >> 3);
    const size_t wofs = (size_t)bx * 65536 + tid * 8;
    const size_t dofs = (size_t)by * 65536 + tid * 8;
    const int t16 = tid * 8;

    f32x16v acc_h[2][2] = {};
    f32x16v acc_l[2][2] = {};

#define STAGE1(buf, tt) do { \
        const size_t so = (size_t)(tt) * 4096; \
        gload16h(Wh + wofs + so,        &lds[buf][0][t16]); \
        gload16h(Wh + wofs + so + 2048, &lds[buf][0][2048 + t16]); \
        gload16h(Wl + wofs + so,        &lds[buf][1][t16]); \
        gload16h(Wl + wofs + so + 2048, &lds[buf][1][2048 + t16]); \
        gload16h(Dh + dofs + so,        &lds[buf][2][t16]); \
        gload16h(Dh + dofs + so + 2048, &lds[buf][2][2048 + t16]); \
        gload16h(Dl + dofs + so,        &lds[buf][3][t16]); \
        gload16h(Dl + dofs + so + 2048, &lds[buf][3][2048 + t16]); \
    } while (0)

    STAGE1(0, 0);

    for (int t = 0; t < 16; ++t) {
        const int cur = t & 1;
        if (t + 1 < 16) {
            STAGE1(cur ^ 1, t + 1);
            asm volatile("s_waitcnt vmcnt(8)" ::: "memory");
        } else {
            asm volatile("s_waitcnt vmcnt(0)" ::: "memory");
        }
        __builtin_amdgcn_s_barrier();

        f16x8 ah[2][2], al[2][2], bh[2][2], bl[2][2];
#pragma unroll
        for (int kcl = 0; kcl < 2; ++kcl)
#pragma unroll
            for (int i = 0; i < 2; ++i) {
                int ao = kcl * 2048 + (wm * 2 + i) * 512 + lane * 8;
                int bo = kcl * 2048 + (wn * 2 + i) * 512 + lane * 8;
                ah[kcl][i] = *reinterpret_cast<const f16x8*>(&lds[cur][0][ao]);
                al[kcl][i] = *reinterpret_cast<const f16x8*>(&lds[cur][1][ao]);
                bh[kcl][i] = *reinterpret_cast<const f16x8*>(&lds[cur][2][bo]);
                bl[kcl][i] = *reinterpret_cast<const f16x8*>(&lds[cur][3][bo]);
            }
        __builtin_amdgcn_s_setprio(1);
#pragma unroll
        for (int kcl = 0; kcl < 2; ++kcl)
#pragma unroll
            for (int i = 0; i < 2; ++i)
#pragma unroll
                for (int j = 0; j < 2; ++j) {
                    acc_h[i][j] = __builtin_amdgcn_mfma_f32_32x32x16_f16(ah[kcl][i], bh[kcl][j], acc_h[i][j], 0, 0, 0);
                    acc_l[i][j] = __builtin_amdgcn_mfma_f32_32x32x16_f16(ah[kcl][i], bl[kcl][j], acc_l[i][j], 0, 0, 0);
                    acc_l[i][j] = __builtin_amdgcn_mfma_f32_32x32x16_f16(al[kcl][i], bh[kcl][j], acc_l[i][j], 0, 0, 0);
                }
        __builtin_amdgcn_s_setprio(0);
        asm volatile("s_waitcnt lgkmcnt(0)" ::: "memory");
        __builtin_amdgcn_s_barrier();
    }
#undef STAGE1

    // epilogue: z -> sigmoid -> PT[node][batch]
#pragma unroll
    for (int i = 0; i < 2; ++i) {
#pragma unroll
        for (int r = 0; r < 16; ++r) {
            int node = bx * 128 + wm * 64 + i * 32 + ((r & 3) + 8 * (r >> 2) + 4 * (lane >> 5));
            if (node < NNODES) {
                float w0 = W[(size_t)node * 513];
                float bt = beta[node];
#pragma unroll
                for (int j = 0; j < 2; ++j) {
                    float z = acc_h[i][j][r] + acc_l[i][j][r] * 4.8828125e-4f;
                    float s = bt * (z + w0);
                    float p = 1.f / (1.f + expf(-s));
                    PT[(size_t)node * B_ROWS + by * 128 + wn * 64 + j * 32 + (lane & 31)] = p;
                }
            }
        }
    }
}

// ---------------------------------------------------------------------------
// Tree pass: thread = row, one subtree-pair per block, fragment-tiled MU2 out.
// MU2 layout [mb(128)][kc(64)][mt(4)][lane(64)][8]:
//   row = mb*128+mt*32+(ln&31), leaf = kc*16+(ln>>5)*8+j
// ---------------------------------------------------------------------------
__global__ __launch_bounds__(256, 4)
void tree_pass(const float* __restrict__ PT,
               __hip_bfloat16* __restrict__ MU2,
               float* __restrict__ pval,          // [16][16384]
               int*   __restrict__ pidx)          // [16][16384]
{
    const int tid = threadIdx.x;
    const int rb = blockIdx.x & 63;
    const int g  = blockIdx.x >> 6;        // pair 0..15
    const int b  = rb * 256 + tid;

    const int c4 = 15 + g;
    const int n3 = (c4 - 1) >> 1;
    const int n2 = (n3 - 1) >> 1;
    const int n1 = (n2 - 1) >> 1;
    const float pc4 = PT[(size_t)c4 * B_ROWS + b];
    const float pn3 = PT[(size_t)n3 * B_ROWS + b];
    const float pn2 = PT[(size_t)n2 * B_ROWS + b];
    const float pn1 = PT[(size_t)n1 * B_ROWS + b];
    const float pn0 = PT[b];
    float pre = ((c4 & 1) ? pn3 : 1.f - pn3)
              * ((n3 & 1) ? pn2 : 1.f - pn2)
              * ((n2 & 1) ? pn1 : 1.f - pn1)
              * ((n1 & 1) ? pn0 : 1.f - pn0);
    float root[2] = { pre * pc4, pre * (1.f - pc4) };

    __align__(16) __hip_bfloat16 mbv[64];
    float bestv = -1.f; int besti = 0;
#pragma unroll
    for (int ss = 0; ss < 2; ++ss) {
        const int t = 2 * g + ss;
        float s[32];
#pragma unroll
        for (int u = 1; u < 32; ++u) {
            int lvl = 31 - __clz(u);
            int node = ((32 << lvl) - 1) + t * (1 << lvl) + (u - (1 << lvl));
            s[u] = PT[(size_t)node * B_ROWS + b];
        }
        float w[64];
        w[1] = root[ss];
#pragma unroll
        for (int u = 1; u < 32; ++u) {
            w[2 * u]     = w[u] * s[u];
            w[2 * u + 1] = w[u] * (1.f - s[u]);
        }
#pragma unroll
        for (int q = 0; q < 32; ++q) {
            float lv = w[32 + q];
            mbv[ss * 32 + q] = __float2bfloat16(lv);
            if (lv > bestv) { bestv = lv; besti = t * 32 + q; }
        }
    }
    // scatter into fragment-tiled MU2: 8x 16B coalesced stores
    {
        const int mb_ = b >> 7, mt_ = (b >> 5) & 3, lnlo = b & 31;
        const ulonglong2* src = reinterpret_cast<const ulonglong2*>(mbv);
#pragma unroll
        for (int c = 0; c < 4; ++c) {
            size_t base16 = (((size_t)mb_ * 64 + g * 4 + c) * 4 + mt_) * 64;
            *reinterpret_cast<ulonglong2*>(&MU2[(base16 + lnlo) * 8])      = src[c * 2];
            *reinterpret_cast<ulonglong2*>(&MU2[(base16 + 32 + lnlo) * 8]) = src[c * 2 + 1];
        }
    }
    pval[(size_t)g * B_ROWS + b] = bestv;
    pidx[(size_t)g * B_ROWS + b] = besti;
}

// ---------------------------------------------------------------------------
// colsum on MU2: grid 256 = kc(64) x mbg(4); block reduces 16 leaves over
// 4096 rows -> partial[mbg][1024]. No atomics.
// ---------------------------------------------------------------------------
__global__ __launch_bounds__(256)
void colsum(const __hip_bfloat16* __restrict__ MU2, float* __restrict__ partial)
{
    __shared__ float red[4][2][8];
    const int blk = blockIdx.x;
    const int kc = blk >> 2, mbg = blk & 3;
    const int t = threadIdx.x;
    const int w = t >> 6, ln = t & 63;
    float a[8] = {0.f, 0.f, 0.f, 0.f, 0.f, 0.f, 0.f, 0.f};
    for (int it = 0; it < 32; ++it) {
        int it2 = it * 4 + w;
        int mb = mbg * 32 + (it2 >> 2), mt = it2 & 3;
        size_t a16 = (((size_t)mb * 64 + kc) * 4 + mt) * 64 + ln;
        ulonglong2 u = *reinterpret_cast<const ulonglong2*>(&MU2[a16 * 8]);
        const unsigned short* hs = reinterpret_cast<const unsigned short*>(&u);
#pragma unroll
        for (int j = 0; j < 8; ++j) a[j] += bf2f(hs[j]);
    }
#pragma unroll
    for (int m = 1; m < 32; m <<= 1)
#pragma unroll
        for (int j = 0; j < 8; ++j) a[j] += __shfl_xor(a[j], m, 64);
    if ((ln & 31) == 0) {
#pragma unroll
        for (int j = 0; j < 8; ++j) red[w][ln >> 5][j] = a[j];
    }
    __syncthreads();
    if (t < 16) {
        float s = red[0][t >> 3][t & 7] + red[1][t >> 3][t & 7]
                + red[2][t >> 3][t & 7] + red[3][t >> 3][t & 7];
        partial[(size_t)mbg * NLEAF + kc * 16 + t] = s;
    }
}

// ---------------------------------------------------------------------------
// softmax over param rows -> logdist (f32) + DT2 (bf16 fragment-tiled
// [kc(64)][nt(8)][lane(64)][8]: col=nt*32+(ln&31), leaf=kc*16+(ln>>5)*8+j)
// ---------------------------------------------------------------------------
__global__ __launch_bounds__(256)
void softmax_param(const float* __restrict__ param,
                   float* __restrict__ logdist,
                   __hip_bfloat16* __restrict__ DT2)
{
    __shared__ float red[4], red2[4];
    int l = blockIdx.x;
    int o = threadIdx.x;
    float x = param[(size_t)l * ODIM + o];
    float m = x;
#pragma unroll
    for (int s = 1; s < 64; s <<= 1) m = fmaxf(m, __shfl_xor(m, s, 64));
    if ((o & 63) == 0) red[o >> 6] = m;
    __syncthreads();
    m = fmaxf(fmaxf(red[0], red[1]), fmaxf(red[2], red[3]));
    float e = expf(x - m);
    float s = e;
#pragma unroll
    for (int k = 1; k < 64; k <<= 1) s += __shfl_xor(s, k, 64);
    if ((o & 63) == 0) red2[o >> 6] = s;
    __syncthreads();
    s = red2[0] + red2[1] + red2[2] + red2[3];
    float d = e / s;
    logdist[(size_t)l * ODIM + o] = logf(d);
    int kc = l >> 4, kk = l & 15;
    int lane = (o & 31) | ((kk >> 3) << 5);
    DT2[(((size_t)kc * 8 + (o >> 5)) * 64 + lane) * 8 + (kk & 7)] = __float2bfloat16(d);
}

// ---------------------------------------------------------------------------
// penalty: reduce 4 partials, heap-aggregate, sum log terms.
// ---------------------------------------------------------------------------
__global__ __launch_bounds__(256)
void penalty_kernel(const float* __restrict__ partial, float* __restrict__ out_pen)
{
    __shared__ float M[2048];
    __shared__ double dred[256];
    int tid = threadIdx.x;
    for (int i = tid; i < 1024; i += 256)
        M[1024 + i] = partial[i] + partial[NLEAF + i] + partial[2 * NLEAF + i] + partial[3 * NLEAF + i];
    __syncthreads();
    for (int n = 512; n >= 1; n >>= 1) {
        for (int u = n + tid; u < 2 * n; u += 256) M[u] = M[2 * u] + M[2 * u + 1];
        __syncthreads();
    }
    double acc = 0.0;
    for (int u = 2 + tid; u < 2048; u += 256) {
        int lvl = 31 - __clz(u);
        float a = M[u] / (M[u >> 1] + EPSV);
        a = fminf(fmaxf(a, EPSV), 1.f - EPSV);
        float term = logf(a) + logf(1.f - a);
        acc -= ldexp((double)LAMDA * 0.5, 1 - lvl) * (double)term;
    }
    dred[tid] = acc;
    __syncthreads();
    for (int s = 128; s > 0; s >>= 1) {
        if (tid < s) dred[tid] += dred[tid + s];
        __syncthreads();
    }
    if (tid == 0) out_pen[0] = (float)dred[0];
}

// ---------------------------------------------------------------------------
// GEMM2: out1 = log(MU2 @ DT2), M-tile 64, N=256, BK=32, dbuf gload_lds.
// grid 256, 4 waves; wave w covers cols w*64..w*64+63 (Mf=2,Nf=2).
// B staging: BOTH kc slices (kc0 -> ldsB[0..4095], kc0+1 -> ldsB[4096..8191]).
// ---------------------------------------------------------------------------
__global__ __launch_bounds__(256)
void gemm2_log(const __hip_bfloat16* __restrict__ MU2,
               const __hip_bfloat16* __restrict__ DT2,
               float* __restrict__ out1)
{
    __shared__ __hip_bfloat16 ldsA[2][2048];   // 2 x 4KB
    __shared__ __hip_bfloat16 ldsB[2][8192];   // 2 x 16KB (two kc slices)
    const int tid = threadIdx.x;
    const int lane = tid & 63;
    const int w = tid >> 6;
    const int blk = blockIdx.x;
    const int m0 = blk * 64;
    const int mb = blk >> 1;
    const int mtbase = (blk & 1) * 2;
    const int s_kcl = tid >> 7, s_mti = (tid >> 6) & 1, s_ln = tid & 63;

    f32x16v acc[2][2] = {};

#define STAGE2(buf, kc0) do { \
        size_t sa16 = (((size_t)mb * 64 + (kc0) + s_kcl) * 4 + mtbase + s_mti) * 64 + s_ln; \
        gload16b(MU2 + sa16 * 8, &ldsA[buf][tid * 8]); \
        gload16b(DT2 + ((size_t)(kc0) * 512 + tid) * 8,             &ldsB[buf][tid * 8]); \
        gload16b(DT2 + ((size_t)(kc0) * 512 + 256 + tid) * 8,       &ldsB[buf][2048 + tid * 8]); \
        gload16b(DT2 + ((size_t)((kc0) + 1) * 512 + tid) * 8,       &ldsB[buf][4096 + tid * 8]); \
        gload16b(DT2 + ((size_t)((kc0) + 1) * 512 + 256 + tid) * 8, &ldsB[buf][6144 + tid * 8]); \
    } while (0)

    STAGE2(0, 0);
    for (int it = 0; it < 32; ++it) {
        const int cur = it & 1;
        if (it + 1 < 32) {
            STAGE2(cur ^ 1, 2 * (it + 1));
            asm volatile("s_waitcnt vmcnt(5)" ::: "memory");
        } else {
            asm volatile("s_waitcnt vmcnt(0)" ::: "memory");
        }
        __builtin_amdgcn_s_barrier();
        bf16x8v a[2][2], bb[2][2];
#pragma unroll
        for (int kcl = 0; kcl < 2; ++kcl)
#pragma unroll
            for (int i = 0; i < 2; ++i) {
                a[kcl][i]  = *reinterpret_cast<const bf16x8v*>(&ldsA[cur][((kcl * 2 + i) * 64 + lane) * 8]);
                bb[kcl][i] = *reinterpret_cast<const bf16x8v*>(&ldsB[cur][((kcl * 8 + 2 * w + i) * 64 + lane) * 8]);
            }
        __builtin_amdgcn_s_setprio(1);
#pragma unroll
        for (int kcl = 0; kcl < 2; ++kcl)
#pragma unroll
            for (int i = 0; i < 2; ++i)
#pragma unroll
                for (int j = 0; j < 2; ++j)
                    acc[i][j] = __builtin_amdgcn_mfma_f32_32x32x16_bf16(a[kcl][i], bb[kcl][j], acc[i][j], 0, 0, 0);
        __builtin_amdgcn_s_setprio(0);
        asm volatile("s_waitcnt lgkmcnt(0)" ::: "memory");
        __builtin_amdgcn_s_barrier();
    }
#undef STAGE2
#pragma unroll
    for (int i = 0; i < 2; ++i)
#pragma unroll
        for (int j = 0; j < 2; ++j)
#pragma unroll
            for (int r = 0; r < 16; ++r) {
                int row = m0 + i * 32 + (r & 3) + 8 * (r >> 2) + 4 * (lane >> 5);
                int col = w * 64 + j * 32 + (lane & 31);
                out1[(size_t)row * ODIM + col] = logf(acc[i][j][r]);
            }
}

// ---------------------------------------------------------------------------
// fused argmax over 16 partials + gather of logdist rows.
// ---------------------------------------------------------------------------
__global__ __launch_bounds__(256)
void argmax_gather(const float* __restrict__ pval, const int* __restrict__ pidx,
                   const float* __restrict__ logdist, float* __restrict__ out0)
{
    __shared__ int sid[64];
    const int blk = blockIdx.x;      // 256 blocks x 64 rows
    const int t = threadIdx.x;
    if (t < 64) {
        int row = blk * 64 + t;
        float bv = -1.f; int bi = 0;
        for (int g = 0; g < 16; ++g) {
            float v = pval[(size_t)g * B_ROWS + row];
            if (v > bv) { bv = v; bi = pidx[(size_t)g * B_ROWS + row]; }
        }
        sid[t] = bi;
    }
    __syncthreads();
    for (int rr = 0; rr < 64; ++rr) {
        int id = sid[rr];
        out0[(size_t)(blk * 64 + rr) * ODIM + t] = logdist[(size_t)id * ODIM + t];
    }
}

__global__ void copy_w(const float* __restrict__ W, float* __restrict__ outW)
{
    int i = blockIdx.x * 256 + threadIdx.x;
    if (i < NNODES * 513) outW[i] = W[i];
}

// ---------------------------------------------------------------------------
extern "C" void kernel_launch(void* const* d_in, const int* in_sizes, int n_in,
                              void* d_out, int out_size, void* d_ws, size_t ws_size,
                              hipStream_t stream)
{
    (void)in_sizes; (void)n_in; (void)out_size; (void)ws_size;
    const float* data  = (const float*)d_in[0];
    const float* W     = (const float*)d_in[1];
    const float* beta  = (const float*)d_in[2];
    const float* param = (const float*)d_in[3];
    float* out = (float*)d_out;

    char* ws = (char*)d_ws;
    size_t off = 0;
    float* PT = (float*)(ws + off);                   off += (size_t)NNODES * B_ROWS * 4;   // 67.04 MB
    char* X = ws + off;                               off += 2 * 1048576 + 2 * 16777216;    // 35.65 MB
    _Float16* Wh = (_Float16*)(X);
    _Float16* Wl = (_Float16*)(X + 1048576);
    _Float16* Dh = (_Float16*)(X + 2 * 1048576);
    _Float16* Dl = (_Float16*)(X + 2 * 1048576 + 16777216);
    __hip_bfloat16* MU2 = (__hip_bfloat16*)(X + 2 * 1048576);  // overlays Dh+Dl (33.55 MB)
    __hip_bfloat16* DT2 = (__hip_bfloat16*)(ws + off); off += (size_t)ODIM * NLEAF * 2;
    float* logdist = (float*)(ws + off);              off += (size_t)NLEAF * ODIM * 4;
    float* partial = (float*)(ws + off);              off += (size_t)4 * NLEAF * 4;
    float* pval    = (float*)(ws + off);              off += (size_t)16 * B_ROWS * 4;
    int*   pidx    = (int*)(ws + off);                off += (size_t)16 * B_ROWS * 4;

    float* out_logpred = out;
    float* out_logout  = out + (size_t)B_ROWS * ODIM;
    float* out_pen     = out + 2 * (size_t)B_ROWS * ODIM;
    float* out_W       = out_pen + 1;

    prep_data<<<4096, 256, 0, stream>>>(data, Dh, Dl);
    prep_w<<<256, 256, 0, stream>>>(W, Wh, Wl);
    softmax_param<<<NLEAF, 256, 0, stream>>>(param, logdist, DT2);

    gemm1_mfma<<<1024, 256, 0, stream>>>(Wh, Wl, Dh, Dl, W, beta, PT);

    tree_pass<<<1024, 256, 0, stream>>>(PT, MU2, pval, pidx);
    colsum<<<256, 256, 0, stream>>>(MU2, partial);
    penalty_kernel<<<1, 256, 0, stream>>>(partial, out_pen);

    gemm2_log<<<B_ROWS / 64, 256, 0, stream>>>(MU2, DT2, out_logout);
    argmax_gather<<<B_ROWS / 64, 256, 0, stream>>>(pval, pidx, logdist, out_logpred);
    copy_w<<<(NNODES * 513 + 255) / 256, 256, 0, stream>>>(W, out_W);
}